// Round 1
// baseline (376.328 us; speedup 1.0000x reference)
//
#include <hip/hip_runtime.h>

#define N 8192
#define CIN 256

typedef __attribute__((ext_vector_type(8))) short short8;   // 8 x bf16 MFMA frag
typedef __attribute__((ext_vector_type(4))) float f32x4;    // MFMA acc
typedef __attribute__((ext_vector_type(4))) unsigned uint4_;
typedef __attribute__((ext_vector_type(2))) unsigned uint2_;

// ws layout (bf16/ushort elements):
// qtA [8192][32] @ 0        ktA @ 262144   qtB @ 524288   ktB @ 786432
// vA  [256][8192] @ 1048576 vB @ 3145728   (total 5,242,880 elems = 10.5 MB)
#define OFF_QTA 0u
#define OFF_KTA 262144u
#define OFF_QTB 524288u
#define OFF_KTB 786432u
#define OFF_VA  1048576u
#define OFF_VB  3145728u

__device__ __forceinline__ unsigned short f2bf(float f) {
    unsigned u = __builtin_bit_cast(unsigned, f);
    u += 0x7fffu + ((u >> 16) & 1u);           // RNE
    return (unsigned short)(u >> 16);
}
__device__ __forceinline__ unsigned packbf2(float a, float b) {
    return (unsigned)f2bf(a) | ((unsigned)f2bf(b) << 16);
}

// ---------------- projection kernel ----------------
// out[o][n] = sum_c W[o][c] x[c][n] + b[o]; Q/K stored transposed [n][32] bf16,
// V stored [o][n] bf16. grid (32 n-tiles, 40 row-groups), 256 thr.
__global__ __launch_bounds__(256) void proj_kernel(
    const float* __restrict__ x,
    const float* __restrict__ WqA, const float* __restrict__ bqA,
    const float* __restrict__ WkA, const float* __restrict__ bkA,
    const float* __restrict__ WvA, const float* __restrict__ bvA,
    const float* __restrict__ WqB, const float* __restrict__ bqB,
    const float* __restrict__ WkB, const float* __restrict__ bkB,
    const float* __restrict__ WvB, const float* __restrict__ bvB,
    unsigned short* __restrict__ ws)
{
    const int t = threadIdx.x;
    const int n = blockIdx.x * 256 + t;
    const int rg = blockIdx.y;

    const float* W; const float* bias; unsigned short* dst; int orel; int trans;
    if (rg < 2)       { W = WqA; bias = bqA; dst = ws + OFF_QTA; orel = rg * 16;        trans = 1; }
    else if (rg < 4)  { W = WkA; bias = bkA; dst = ws + OFF_KTA; orel = (rg - 2) * 16;  trans = 1; }
    else if (rg < 20) { W = WvA; bias = bvA; dst = ws + OFF_VA;  orel = (rg - 4) * 16;  trans = 0; }
    else if (rg < 22) { W = WqB; bias = bqB; dst = ws + OFF_QTB; orel = (rg - 20) * 16; trans = 1; }
    else if (rg < 24) { W = WkB; bias = bkB; dst = ws + OFF_KTB; orel = (rg - 22) * 16; trans = 1; }
    else              { W = WvB; bias = bvB; dst = ws + OFF_VB;  orel = (rg - 24) * 16; trans = 0; }

    float acc[16];
    #pragma unroll
    for (int o = 0; o < 16; ++o) acc[o] = bias[orel + o];

    for (int c0 = 0; c0 < CIN; c0 += 8) {
        float xv[8];
        #pragma unroll
        for (int k = 0; k < 8; ++k) xv[k] = x[(c0 + k) * N + n];
        #pragma unroll
        for (int o = 0; o < 16; ++o) {
            const float* wr = W + (orel + o) * CIN + c0;   // wave-uniform -> s_load
            float s0 = wr[0]*xv[0] + wr[1]*xv[1] + wr[2]*xv[2] + wr[3]*xv[3];
            float s1 = wr[4]*xv[4] + wr[5]*xv[5] + wr[6]*xv[6] + wr[7]*xv[7];
            acc[o] += s0 + s1;
        }
    }

    if (trans) {
        unsigned pk[8];
        #pragma unroll
        for (int q = 0; q < 8; ++q) pk[q] = packbf2(acc[2*q], acc[2*q+1]);
        unsigned* p = (unsigned*)(dst + (size_t)n * 32 + orel);
        *(uint4_*)(p)     = (uint4_){pk[0], pk[1], pk[2], pk[3]};
        *(uint4_*)(p + 4) = (uint4_){pk[4], pk[5], pk[6], pk[7]};
    } else {
        #pragma unroll
        for (int o = 0; o < 16; ++o) dst[(size_t)(orel + o) * N + n] = f2bf(acc[o]);
    }
}

// ---------------- fused flash-attention kernel ----------------
// grid 256 = 2 dirs x 128 q-blocks (QBLK=64). 512 thr = 8 waves.
// S^T = mfma(Kfrag, Qfrag): D[row=m(4g+i)][col=n(l&15)] -> lane-local softmax rows.
// waves 0-3: S^T + softmax for n-tile ct=w, write P/alpha to LDS, 1 PV c-tile.
// waves 4-7: 3 PV c-tiles each. One barrier/step, P double-buffered.
__global__ __launch_bounds__(512) void attn_kernel(
    const float* __restrict__ x,
    const unsigned short* __restrict__ ws,
    const float* __restrict__ gammaA, const float* __restrict__ gammaB,
    float* __restrict__ out)
{
    __shared__ unsigned short Pbuf[2][64][72];   // [buf][n_local][m_local(+pad)]
    __shared__ float Abuf[2][64];                // alpha per n_local
    __shared__ float Lbuf[64];

    const int tid = threadIdx.x;
    const int w = tid >> 6, l = tid & 63, g = l >> 4, lc = l & 15;
    const int bid = blockIdx.x;
    const int dir = bid & 1;          // 0: (QB,KA,VA)->task2 ; 1: (QA,KB,VB)->task1
    const int n0 = (bid >> 1) * 64;

    const unsigned short* qt = ws + (dir ? OFF_QTA : OFF_QTB);
    const unsigned short* kt = ws + (dir ? OFF_KTB : OFF_KTA);
    const unsigned short* V  = ws + (dir ? OFF_VB  : OFF_VA);
    const float gamma = dir ? gammaA[0] : gammaB[0];
    float* outp = out + (dir ? 0u : (unsigned)CIN * N);

    const bool sw = (w < 4);
    const int ct  = w & 3;                       // softmax n-tile for S-waves
    const int ct0 = sw ? w : 4 + (w - 4) * 3;    // first PV c-tile
    const int nct = sw ? 1 : 3;

    const float L2E = 1.4426950408889634f;

    short8 qf = {};
    if (sw) qf = *(const short8*)(qt + (n0 + ct * 16 + lc) * 32 + 8 * g);

    f32x4 acc[3][4];
    #pragma unroll
    for (int u = 0; u < 3; ++u)
        #pragma unroll
        for (int j = 0; j < 4; ++j) acc[u][j] = (f32x4){0.f, 0.f, 0.f, 0.f};
    float M = -1e30f, L = 0.f;

    for (int s = 0; s < 128; ++s) {
        const int m0 = s * 64;
        const int buf = s & 1;

        if (sw) {
            f32x4 sv[4];
            #pragma unroll
            for (int t = 0; t < 4; ++t) {
                short8 kf = *(const short8*)(kt + (m0 + 16 * t + lc) * 32 + 8 * g);
                sv[t] = __builtin_amdgcn_mfma_f32_16x16x32_bf16(
                            kf, qf, (f32x4){0.f, 0.f, 0.f, 0.f}, 0, 0, 0);
            }
            float xm = -1e30f;
            #pragma unroll
            for (int t = 0; t < 4; ++t)
                #pragma unroll
                for (int i = 0; i < 4; ++i) xm = fmaxf(xm, sv[t][i]);
            xm = fmaxf(xm, __shfl_xor(xm, 16));
            xm = fmaxf(xm, __shfl_xor(xm, 32));
            const float Mn = fmaxf(M, xm);
            const float al = exp2f((M - Mn) * L2E);
            float rs = 0.f;
            float p[4][4];
            #pragma unroll
            for (int t = 0; t < 4; ++t)
                #pragma unroll
                for (int i = 0; i < 4; ++i) {
                    p[t][i] = exp2f((sv[t][i] - Mn) * L2E);
                    rs += p[t][i];
                }
            rs += __shfl_xor(rs, 16);
            rs += __shfl_xor(rs, 32);
            L = L * al + rs;
            M = Mn;

            const int nl = ct * 16 + lc;
            #pragma unroll
            for (int t = 0; t < 4; ++t) {
                uint2_ u2;
                u2.x = packbf2(p[t][0], p[t][1]);
                u2.y = packbf2(p[t][2], p[t][3]);
                *(uint2_*)&Pbuf[buf][nl][16 * t + 4 * g] = u2;   // m = 16t+4g..+3
            }
            if (g == 0) Abuf[buf][nl] = al;
        }
        __syncthreads();

        float av[4];
        #pragma unroll
        for (int j = 0; j < 4; ++j) av[j] = Abuf[buf][16 * j + lc];

        short8 pf[4][2];
        #pragma unroll
        for (int j = 0; j < 4; ++j)
            #pragma unroll
            for (int h = 0; h < 2; ++h)
                pf[j][h] = *(const short8*)&Pbuf[buf][16 * j + lc][32 * h + 8 * g];

        #pragma unroll
        for (int u = 0; u < 3; ++u) {
            if (u < nct) {
                #pragma unroll
                for (int j = 0; j < 4; ++j) acc[u][j] *= av[j];
                const unsigned short* vp = V + (size_t)((ct0 + u) * 16 + lc) * N + m0;
                short8 vf0 = *(const short8*)(vp + 8 * g);
                short8 vf1 = *(const short8*)(vp + 32 + 8 * g);
                #pragma unroll
                for (int j = 0; j < 4; ++j) {
                    acc[u][j] = __builtin_amdgcn_mfma_f32_16x16x32_bf16(vf0, pf[j][0], acc[u][j], 0, 0, 0);
                    acc[u][j] = __builtin_amdgcn_mfma_f32_16x16x32_bf16(vf1, pf[j][1], acc[u][j], 0, 0, 0);
                }
            }
        }
        // no trailing barrier: next step writes the other P buffer; the step-s+1
        // barrier orders those writes after all step-s reads.
    }

    __syncthreads();
    if (sw && g == 0) Lbuf[ct * 16 + lc] = L;
    __syncthreads();

    float rl[4];
    #pragma unroll
    for (int j = 0; j < 4; ++j) rl[j] = 1.0f / Lbuf[16 * j + lc];

    #pragma unroll
    for (int u = 0; u < 3; ++u) {
        if (u < nct) {
            #pragma unroll
            for (int j = 0; j < 4; ++j) {
                #pragma unroll
                for (int i = 0; i < 4; ++i) {
                    const int c = (ct0 + u) * 16 + 4 * g + i;   // D row = 4g+i
                    const int n = n0 + 16 * j + lc;             // D col = l&15
                    const size_t off = (size_t)c * N + n;
                    outp[off] = gamma * acc[u][j][i] * rl[j] + x[off];
                }
            }
        }
    }
}

extern "C" void kernel_launch(void* const* d_in, const int* in_sizes, int n_in,
                              void* d_out, int out_size, void* d_ws, size_t ws_size,
                              hipStream_t stream) {
    const float* x = (const float*)d_in[0];
    unsigned short* ws = (unsigned short*)d_ws;

    dim3 pg(32, 40);
    proj_kernel<<<pg, 256, 0, stream>>>(
        x,
        (const float*)d_in[1],  (const float*)d_in[2],
        (const float*)d_in[3],  (const float*)d_in[4],
        (const float*)d_in[5],  (const float*)d_in[6],
        (const float*)d_in[7],  (const float*)d_in[8],
        (const float*)d_in[9],  (const float*)d_in[10],
        (const float*)d_in[11], (const float*)d_in[12],
        ws);

    attn_kernel<<<256, 512, 0, stream>>>(
        x, ws,
        (const float*)d_in[13], (const float*)d_in[14],
        (float*)d_out);
}

// Round 2
// 273.525 us; speedup vs baseline: 1.3758x; 1.3758x over previous
//
#include <hip/hip_runtime.h>

#define N 8192
#define CIN 256
#define C8 32
#define QBLK 128
#define KVB 64

typedef __attribute__((ext_vector_type(8))) short short8;   // 8 x bf16 MFMA frag
typedef __attribute__((ext_vector_type(4))) float f32x4;
typedef __attribute__((ext_vector_type(2))) float f32x2;
typedef __attribute__((ext_vector_type(4))) float float4_;
typedef __attribute__((ext_vector_type(4))) unsigned uint4_;
typedef __attribute__((ext_vector_type(2))) unsigned uint2_;

// ---- ws layout ----
// proj outputs (ushort/bf16): qtA [8192][32] @0, ktA, qtB, ktB, vA [256][8192], vB
#define OFF_QTA 0u
#define OFF_KTA 262144u
#define OFF_QTB 524288u
#define OFF_KTB 786432u
#define OFF_VA  1048576u
#define OFF_VB  3145728u
#define PROJ_USHORTS 5242880u
// then: accb bf16 [2*64*SP][256][128]; then Lpart f32 [2*64*SP][128]

__device__ __forceinline__ unsigned short f2bf(float f) {
    unsigned u = __builtin_bit_cast(unsigned, f);
    u += 0x7fffu + ((u >> 16) & 1u);           // RNE
    return (unsigned short)(u >> 16);
}
__device__ __forceinline__ unsigned packbf2(float a, float b) {
    return (unsigned)f2bf(a) | ((unsigned)f2bf(b) << 16);
}
__device__ __forceinline__ float bf2f(unsigned short u) {
    return __builtin_bit_cast(float, (unsigned)u << 16);
}

// XOR-swizzled LDS byte offset: row stride 128B (8 slots x 16B), slot holds m-chunk (slot^(row&7))
__device__ __forceinline__ int swz_off(int row, int mu) {
    return (row << 7) + (((mu ^ (row & 7)) & 7) << 4);
}

// ---------------- projection kernel ----------------
__global__ __launch_bounds__(256) void proj_kernel(
    const float* __restrict__ x,
    const float* __restrict__ WqA, const float* __restrict__ bqA,
    const float* __restrict__ WkA, const float* __restrict__ bkA,
    const float* __restrict__ WvA, const float* __restrict__ bvA,
    const float* __restrict__ WqB, const float* __restrict__ bqB,
    const float* __restrict__ WkB, const float* __restrict__ bkB,
    const float* __restrict__ WvB, const float* __restrict__ bvB,
    unsigned short* __restrict__ ws)
{
    __shared__ __align__(16) float Wlds[16 * 256];

    const int t = threadIdx.x;
    const int n = blockIdx.x * 256 + t;
    const int rg = blockIdx.y;

    const float* W; const float* bias; unsigned short* dst; int orel; int trans;
    if (rg < 2)       { W = WqA; bias = bqA; dst = ws + OFF_QTA; orel = rg * 16;        trans = 1; }
    else if (rg < 4)  { W = WkA; bias = bkA; dst = ws + OFF_KTA; orel = (rg - 2) * 16;  trans = 1; }
    else if (rg < 20) { W = WvA; bias = bvA; dst = ws + OFF_VA;  orel = (rg - 4) * 16;  trans = 0; }
    else if (rg < 22) { W = WqB; bias = bqB; dst = ws + OFF_QTB; orel = (rg - 20) * 16; trans = 1; }
    else if (rg < 24) { W = WkB; bias = bkB; dst = ws + OFF_KTB; orel = (rg - 22) * 16; trans = 1; }
    else              { W = WvB; bias = bvB; dst = ws + OFF_VB;  orel = (rg - 24) * 16; trans = 0; }

    // stage W rows [orel..orel+15] (flat 4096 floats) into LDS, coalesced float4
    {
        const float4_* Wg = (const float4_*)(W + (size_t)orel * CIN);
        float4_* Wl = (float4_*)Wlds;
        #pragma unroll
        for (int b = 0; b < 4; ++b) Wl[b * 256 + t] = Wg[b * 256 + t];
    }
    __syncthreads();

    f32x2 acc2[16];
    #pragma unroll
    for (int o = 0; o < 16; ++o) acc2[o] = (f32x2){0.f, 0.f};

    const f32x2* W2 = (const f32x2*)Wlds;
    for (int c0 = 0; c0 < CIN; c0 += 8) {
        f32x2 xv[4];
        #pragma unroll
        for (int k = 0; k < 4; ++k) {
            xv[k].x = x[(size_t)(c0 + 2 * k) * N + n];
            xv[k].y = x[(size_t)(c0 + 2 * k + 1) * N + n];
        }
        #pragma unroll
        for (int o = 0; o < 16; ++o) {
            const f32x2* wr = W2 + o * 128 + (c0 >> 1);   // LDS broadcast reads
            #pragma unroll
            for (int k = 0; k < 4; ++k) acc2[o] += wr[k] * xv[k];
        }
    }

    float acc[16];
    #pragma unroll
    for (int o = 0; o < 16; ++o) acc[o] = acc2[o].x + acc2[o].y + bias[orel + o];

    if (trans) {
        unsigned pk[8];
        #pragma unroll
        for (int q = 0; q < 8; ++q) pk[q] = packbf2(acc[2*q], acc[2*q+1]);
        unsigned* p = (unsigned*)(dst + (size_t)n * 32 + orel);
        *(uint4_*)(p)     = (uint4_){pk[0], pk[1], pk[2], pk[3]};
        *(uint4_*)(p + 4) = (uint4_){pk[4], pk[5], pk[6], pk[7]};
    } else {
        #pragma unroll
        for (int o = 0; o < 16; ++o) dst[(size_t)(orel + o) * N + n] = f2bf(acc[o]);
    }
}

// ---------------- fused flash-attention kernel (kv-split, no-max softmax) ----------------
// grid = SP*2*64 blocks, 512 thr (8 waves). Each block: 128 q-cols, m-range N/SP.
// Wave w: S^T+softmax for cols [w*16, w*16+16); PV for channels [w*32, w*32+32).
// V-tile [256][64] staged in LDS via global_load_lds, XOR-swizzled source.
__global__ __launch_bounds__(512, 2) void attn_kernel(
    const unsigned short* __restrict__ ws,
    unsigned short* __restrict__ accb,
    float* __restrict__ Lpart,
    int SP)
{
    __shared__ __align__(16) unsigned short Vt[256 * 64];   // 32 KB
    __shared__ __align__(16) unsigned short Pl[128 * 64];   // 16 KB (single buffer: 2 barriers/step)

    const int tid = threadIdx.x;
    const int w = tid >> 6, l = tid & 63, g = l >> 4, lc = l & 15;
    const int bid = blockIdx.x;
    const int dir = bid & 1;            // 1: (QA,KB,VB)->task1@0 ; 0: (QB,KA,VA)->task2@CIN*N
    const int qb  = (bid >> 1) & 63;
    const int sp  = bid >> 7;
    const int mlen   = N / SP;
    const int m_base = sp * mlen;
    const int NS     = mlen / KVB;

    const unsigned short* qt = ws + (dir ? OFF_QTA : OFF_QTB);
    const unsigned short* kt = ws + (dir ? OFF_KTB : OFF_KTA);
    const unsigned short* V  = ws + (dir ? OFF_VB  : OFF_VA);

    const float L2E = 1.4426950408889634f;

    // this wave's 16 q-cols
    const short8 qf = *(const short8*)(qt + (size_t)(qb * QBLK + w * 16 + lc) * C8 + 8 * g);

    // prologue: stage V tile 0; load K frags for s=0
    #pragma unroll
    for (int h = 0; h < 4; ++h) {
        const int c = ((w * 4 + h) << 3) + (l >> 3);
        const int slot = l & 7;
        const unsigned short* src = V + (size_t)c * N + m_base + (((slot ^ (c & 7)) & 7) << 3);
        unsigned short* dstl = Vt + ((w * 4 + h) << 9);   // wave-uniform base; HW adds lane*16B
        __builtin_amdgcn_global_load_lds((const __attribute__((address_space(1))) unsigned int*)src,
                                         (__attribute__((address_space(3))) unsigned int*)dstl,
                                         16, 0, 0);
    }
    short8 kf[4], kfn[4];
    #pragma unroll
    for (int t = 0; t < 4; ++t)
        kf[t] = *(const short8*)(kt + (size_t)(m_base + 16 * t + lc) * C8 + 8 * g);

    f32x4 acc[2][8];
    #pragma unroll
    for (int u = 0; u < 2; ++u)
        #pragma unroll
        for (int j = 0; j < 8; ++j) acc[u][j] = (f32x4){0.f, 0.f, 0.f, 0.f};
    float Lr = 0.f;

    const int col = w * 16 + lc;   // this lane's q-col (local)

    for (int s = 0; s < NS; ++s) {
        const int m0 = m_base + s * KVB;

        // ---- S phase: S^T = mfma(K,Q); P = exp2(S*log2e); write P to LDS ----
        f32x4 sv[4];
        #pragma unroll
        for (int t = 0; t < 4; ++t)
            sv[t] = __builtin_amdgcn_mfma_f32_16x16x32_bf16(kf[t], qf, (f32x4){0.f,0.f,0.f,0.f}, 0, 0, 0);

        float pr[4][4];
        #pragma unroll
        for (int t = 0; t < 4; ++t)
            #pragma unroll
            for (int i = 0; i < 4; ++i) {
                pr[t][i] = exp2f(fminf(sv[t][i] * L2E, 80.f));
                Lr += pr[t][i];
            }
        #pragma unroll
        for (int t = 0; t < 4; ++t) {
            // lane holds P[m=16t+4g+i][col]; m-chunk = 2t+(g>>1), in-slot byte off = (g&1)*8
            uint2_ u2;
            u2.x = packbf2(pr[t][0], pr[t][1]);
            u2.y = packbf2(pr[t][2], pr[t][3]);
            *(uint2_*)((char*)Pl + swz_off(col, 2 * t + (g >> 1)) + ((g & 1) << 3)) = u2;
        }

        __syncthreads();   // A: V(s) staged (vmcnt drain), P visible

        // prefetch next K frags (register, latency hidden under PV)
        if (s + 1 < NS) {
            #pragma unroll
            for (int t = 0; t < 4; ++t)
                kfn[t] = *(const short8*)(kt + (size_t)(m0 + KVB + 16 * t + lc) * C8 + 8 * g);
        }

        // ---- PV phase: acc[c-tile][col-tile] += V * P ----
        short8 vf[2][2];
        #pragma unroll
        for (int u = 0; u < 2; ++u)
            #pragma unroll
            for (int kc = 0; kc < 2; ++kc)
                vf[u][kc] = *(const short8*)((const char*)Vt + swz_off(w * 32 + u * 16 + lc, kc * 4 + g));

        #pragma unroll
        for (int j = 0; j < 8; ++j) {
            const int colr = j * 16 + lc;
            const short8 pf0 = *(const short8*)((const char*)Pl + swz_off(colr, g));
            const short8 pf1 = *(const short8*)((const char*)Pl + swz_off(colr, 4 + g));
            #pragma unroll
            for (int u = 0; u < 2; ++u) {
                acc[u][j] = __builtin_amdgcn_mfma_f32_16x16x32_bf16(vf[u][0], pf0, acc[u][j], 0, 0, 0);
                acc[u][j] = __builtin_amdgcn_mfma_f32_16x16x32_bf16(vf[u][1], pf1, acc[u][j], 0, 0, 0);
            }
        }

        __syncthreads();   // B: all V/P reads done -> safe to restage

        if (s + 1 < NS) {
            #pragma unroll
            for (int h = 0; h < 4; ++h) {
                const int c = ((w * 4 + h) << 3) + (l >> 3);
                const int slot = l & 7;
                const unsigned short* src = V + (size_t)c * N + (m0 + KVB) + (((slot ^ (c & 7)) & 7) << 3);
                unsigned short* dstl = Vt + ((w * 4 + h) << 9);
                __builtin_amdgcn_global_load_lds((const __attribute__((address_space(1))) unsigned int*)src,
                                                 (__attribute__((address_space(3))) unsigned int*)dstl,
                                                 16, 0, 0);
            }
            #pragma unroll
            for (int t = 0; t < 4; ++t) kf[t] = kfn[t];
        }
    }

    // ---- epilogue: exchange L, store bf16 partials ----
    Lr += __shfl_xor(Lr, 16);
    Lr += __shfl_xor(Lr, 32);
    __syncthreads();
    float* Lsh = (float*)Pl;
    if (g == 0) Lsh[w * 16 + lc] = Lr;
    __syncthreads();

    const size_t blk = (size_t)(dir * 64 + qb) * SP + sp;
    unsigned short* ab = accb + blk * (256 * 128);
    #pragma unroll
    for (int u = 0; u < 2; ++u)
        #pragma unroll
        for (int j = 0; j < 8; ++j)
            #pragma unroll
            for (int i = 0; i < 4; ++i) {
                const int c  = w * 32 + u * 16 + 4 * g + i;   // D row = 4*(l>>4)+i
                const int nl = j * 16 + lc;                   // D col = l&15
                ab[c * 128 + nl] = f2bf(acc[u][j][i]);
            }
    if (tid < 128) Lpart[blk * 128 + tid] = Lsh[tid];
}

// ---------------- combine kernel: out = gamma * (sum acc)/(sum L) + x ----------------
__global__ __launch_bounds__(256) void combine_kernel(
    const float* __restrict__ x,
    const unsigned short* __restrict__ accb,
    const float* __restrict__ Lpart,
    const float* __restrict__ gammaA, const float* __restrict__ gammaB,
    float* __restrict__ out, int SP)
{
    const int tid = blockIdx.x * 256 + threadIdx.x;    // 2^19 threads
    const int nlq = tid & 15;
    const int qb  = (tid >> 4) & 63;
    const int c   = (tid >> 10) & 255;
    const int dir = (tid >> 18) & 1;
    const int nl0 = nlq * 8;

    const size_t bb = (size_t)(dir * 64 + qb) * SP;
    float s[8], Ls[8];
    #pragma unroll
    for (int e = 0; e < 8; ++e) { s[e] = 0.f; Ls[e] = 0.f; }

    for (int sp = 0; sp < SP; ++sp) {
        const unsigned short* ap = accb + (bb + sp) * (256 * 128) + (size_t)c * 128 + nl0;
        const short8 av = *(const short8*)ap;
        const float* lp = Lpart + (bb + sp) * 128 + nl0;
        #pragma unroll
        for (int e = 0; e < 8; ++e) {
            s[e]  += bf2f((unsigned short)av[e]);
            Ls[e] += lp[e];
        }
    }

    const float gamma = dir ? gammaA[0] : gammaB[0];
    const size_t off = (size_t)c * N + qb * QBLK + nl0;
    const float* xp = x + off;
    float* op = out + (dir ? 0 : (size_t)CIN * N) + off;
    #pragma unroll
    for (int e = 0; e < 8; ++e) op[e] = gamma * s[e] / Ls[e] + xp[e];
}

extern "C" void kernel_launch(void* const* d_in, const int* in_sizes, int n_in,
                              void* d_out, int out_size, void* d_ws, size_t ws_size,
                              hipStream_t stream) {
    const float* x = (const float*)d_in[0];
    unsigned short* ws = (unsigned short*)d_ws;

    // pick kv-split by available scratch (ws_size is constant across calls -> graph-safe)
    size_t needed4 = (size_t)PROJ_USHORTS * 2 + 4ull * 8388608 + 4ull * 65536;
    size_t needed2 = (size_t)PROJ_USHORTS * 2 + 2ull * 8388608 + 2ull * 65536;
    int SP = (ws_size >= needed4) ? 4 : (ws_size >= needed2) ? 2 : 1;

    unsigned short* accb = ws + PROJ_USHORTS;
    float* Lpart = (float*)(ws + PROJ_USHORTS + (size_t)SP * 4194304);

    dim3 pg(32, 40);
    proj_kernel<<<pg, 256, 0, stream>>>(
        x,
        (const float*)d_in[1],  (const float*)d_in[2],
        (const float*)d_in[3],  (const float*)d_in[4],
        (const float*)d_in[5],  (const float*)d_in[6],
        (const float*)d_in[7],  (const float*)d_in[8],
        (const float*)d_in[9],  (const float*)d_in[10],
        (const float*)d_in[11], (const float*)d_in[12],
        ws);

    attn_kernel<<<128 * SP, 512, 0, stream>>>(ws, accb, Lpart, SP);

    combine_kernel<<<2048, 256, 0, stream>>>(
        x, accb, Lpart,
        (const float*)d_in[13], (const float*)d_in[14],
        (float*)d_out, SP);
}

// Round 4
// 224.897 us; speedup vs baseline: 1.6733x; 1.2162x over previous
//
#include <hip/hip_runtime.h>

#define N 8192
#define CIN 256
#define C8 32
#define QBLK 64
#define KVB 64
#define L2E 1.4426950408889634f

typedef __attribute__((ext_vector_type(8))) short short8;   // 8 x bf16 MFMA frag
typedef __attribute__((ext_vector_type(4))) float f32x4;
typedef __attribute__((ext_vector_type(4))) float float4_;
typedef __attribute__((ext_vector_type(4))) unsigned short ushort4_;
typedef __attribute__((ext_vector_type(2))) unsigned uint2_;

// ---- ws layout (ushort units) ----
#define OFF_QTA 0u
#define OFF_KTA 262144u
#define OFF_QTB 524288u
#define OFF_KTB 786432u
#define OFF_VA  1048576u
#define OFF_VB  3145728u
#define PROJ_USHORTS 5242880u
// Wb (640x256 bf16, 327KB) overlaps accb start: castW->proj read it, attn then clobbers.
// accb bf16 [2*128*SP][256][64] after proj region; Lpart f32 [2*128*SP][64] after accb.

__device__ __forceinline__ unsigned short f2bf(float f) {
    unsigned u = __builtin_bit_cast(unsigned, f);
    u += 0x7fffu + ((u >> 16) & 1u);           // RNE
    return (unsigned short)(u >> 16);
}
__device__ __forceinline__ unsigned packbf2(float a, float b) {
    return (unsigned)f2bf(a) | ((unsigned)f2bf(b) << 16);
}
__device__ __forceinline__ float bf2f(unsigned short u) {
    return __builtin_bit_cast(float, (unsigned)u << 16);
}

// ---------------- castW: f32 W -> bf16 Wb[640][256], Q rows scaled by log2e ----------------
__global__ __launch_bounds__(256) void castw_kernel(
    const float* __restrict__ WqA, const float* __restrict__ WkA, const float* __restrict__ WvA,
    const float* __restrict__ WqB, const float* __restrict__ WkB, const float* __restrict__ WvB,
    unsigned short* __restrict__ Wb)
{
    const int idx = blockIdx.x * 256 + threadIdx.x;   // 40960 threads x 4 elems
    const int e = idx * 4;
    const int r = e >> 8;                              // global row 0..639
    const float* src; int rel;
    if (r < 32)       { src = WqA; rel = e; }
    else if (r < 64)  { src = WkA; rel = e - 32 * 256; }
    else if (r < 320) { src = WvA; rel = e - 64 * 256; }
    else if (r < 352) { src = WqB; rel = e - 320 * 256; }
    else if (r < 384) { src = WkB; rel = e - 352 * 256; }
    else              { src = WvB; rel = e - 384 * 256; }
    const float sc = (r < 32 || (r >= 320 && r < 352)) ? L2E : 1.0f;
    float4_ v = *(const float4_*)(src + rel);
    ushort4_ o;
    o.x = f2bf(v.x * sc); o.y = f2bf(v.y * sc); o.z = f2bf(v.z * sc); o.w = f2bf(v.w * sc);
    *(ushort4_*)(Wb + e) = o;
}

// ---------------- projection via MFMA ----------------
// grid 256 (n-tiles of 32), 512 thr (8 waves). Wave w owns o-tiles [5w,5w+5) of 40.
// LDS xT[32 n][256 c] bf16, byte-XOR swizzled: byte = n*512 + (2c ^ ((n&7)<<4)).
__global__ __launch_bounds__(512) void proj_kernel(
    const float* __restrict__ x, const unsigned short* __restrict__ Wb,
    const float* __restrict__ bqA, const float* __restrict__ bkA, const float* __restrict__ bvA,
    const float* __restrict__ bqB, const float* __restrict__ bkB, const float* __restrict__ bvB,
    unsigned short* __restrict__ ws)
{
    __shared__ __align__(16) unsigned short xT[32 * 256];   // 16 KB

    const int tid = threadIdx.x;
    const int w = tid >> 6, l = tid & 63, g = l >> 4, lc = l & 15;
    const int n0 = blockIdx.x * 32;

    // stage + transpose x[c][n0..n0+32) -> xT bf16 swizzled
    #pragma unroll
    for (int r = 0; r < 4; ++r) {
        const int flat4 = r * 512 + tid;          // 0..2047
        const int c = flat4 >> 3, nl = (flat4 & 7) * 4;
        float4_ v = *(const float4_*)(x + (size_t)c * N + n0 + nl);
        #pragma unroll
        for (int e = 0; e < 4; ++e) {
            const int nn = nl + e;
            const int byte = nn * 512 + ((2 * c) ^ ((nn & 7) << 4));
            *(unsigned short*)((char*)xT + byte) = f2bf(v[e]);
        }
    }
    __syncthreads();

    f32x4 acc[5][2];
    #pragma unroll
    for (int i = 0; i < 5; ++i)
        #pragma unroll
        for (int ns = 0; ns < 2; ++ns) acc[i][ns] = (f32x4){0.f, 0.f, 0.f, 0.f};

    for (int c0 = 0; c0 < 256; c0 += 32) {
        short8 xf[2];
        #pragma unroll
        for (int ns = 0; ns < 2; ++ns) {
            const int byte = (ns * 16 + lc) * 512 + ((2 * (c0 + 8 * g)) ^ ((lc & 7) << 4));
            xf[ns] = *(const short8*)((const char*)xT + byte);
        }
        #pragma unroll
        for (int i = 0; i < 5; ++i) {
            const int ot = w * 5 + i;
            const short8 wf = *(const short8*)(Wb + (size_t)(ot * 16 + lc) * 256 + c0 + 8 * g);
            const bool isV = (ot >= 4 && ot < 20) || (ot >= 24);
            #pragma unroll
            for (int ns = 0; ns < 2; ++ns)
                acc[i][ns] = isV
                    ? __builtin_amdgcn_mfma_f32_16x16x32_bf16(wf, xf[ns], acc[i][ns], 0, 0, 0)
                    : __builtin_amdgcn_mfma_f32_16x16x32_bf16(xf[ns], wf, acc[i][ns], 0, 0, 0);
        }
    }

    #pragma unroll
    for (int i = 0; i < 5; ++i) {
        const int ot = w * 5 + i;
        const float* bias; unsigned short* dst; int orelm; bool isV = false; float bsc = 1.0f;
        if (ot < 2)       { bias = bqA; dst = ws + OFF_QTA; orelm = ot * 16;        bsc = L2E; }
        else if (ot < 4)  { bias = bkA; dst = ws + OFF_KTA; orelm = (ot - 2) * 16; }
        else if (ot < 20) { bias = bvA; dst = ws + OFF_VA;  orelm = (ot - 4) * 16;  isV = true; }
        else if (ot < 22) { bias = bqB; dst = ws + OFF_QTB; orelm = (ot - 20) * 16; bsc = L2E; }
        else if (ot < 24) { bias = bkB; dst = ws + OFF_KTB; orelm = (ot - 22) * 16; }
        else              { bias = bvB; dst = ws + OFF_VB;  orelm = (ot - 24) * 16; isV = true; }

        if (isV) {
            // D[row=o_loc=4g+ii][col=n=lc] -> V[c][n]
            #pragma unroll
            for (int ii = 0; ii < 4; ++ii) {
                const float b = bias[orelm + 4 * g + ii];
                #pragma unroll
                for (int ns = 0; ns < 2; ++ns)
                    dst[(size_t)(orelm + 4 * g + ii) * N + n0 + ns * 16 + lc] = f2bf(acc[i][ns][ii] + b);
            }
        } else {
            // D^T form: D[row=n=4g+ii][col=o=lc] -> qt/kt[n][32]
            const float b = bias[orelm + lc] * bsc;
            #pragma unroll
            for (int ns = 0; ns < 2; ++ns)
                #pragma unroll
                for (int ii = 0; ii < 4; ++ii)
                    dst[(size_t)(n0 + ns * 16 + 4 * g + ii) * C8 + orelm + lc] = f2bf(acc[i][ns][ii] + b);
        }
    }
}

// ---------------- fused flash-attention (QBLK=64, 1 barrier/step) ----------------
// grid 256*SP, 512 thr (8 waves). Waves 0-3: S^T+softmax for cols [w*16,+16).
// All waves: PV for channels [w*32,+32) x all 64 cols. V,P double-buffered, swizzled.
__global__ __launch_bounds__(512, 4) void attn_kernel(
    const unsigned short* __restrict__ ws,
    unsigned short* __restrict__ accb,
    float* __restrict__ Lpart,
    int SP)
{
    __shared__ __align__(16) unsigned short Vt[2][256 * 64];   // 2 x 32 KB
    __shared__ __align__(16) unsigned short Pl[2][64 * 64];    // 2 x 8 KB

    const int tid = threadIdx.x;
    const int w = tid >> 6, l = tid & 63, g = l >> 4, lc = l & 15;
    const int bid = blockIdx.x;
    const int dir = bid & 1;            // 1: (QA,KB,VB)->task1@0 ; 0: (QB,KA,VA)->task2@CIN*N
    const int qb  = (bid >> 1) & 127;
    const int sp  = bid >> 8;
    const int mlen   = N / SP;
    const int m_base = sp * mlen;
    const int NS     = mlen / KVB;

    const unsigned short* qt = ws + (dir ? OFF_QTA : OFF_QTB);
    const unsigned short* kt = ws + (dir ? OFF_KTB : OFF_KTA);
    const unsigned short* V  = ws + (dir ? OFF_VB  : OFF_VA);

    const bool sw = (w < 4);
    const int col = w * 16 + lc;        // S-wave's local q-col

    short8 qf = {};
    if (sw) qf = *(const short8*)(qt + (size_t)(qb * QBLK + col) * C8 + 8 * g);

    // V staging: wave w stages rows [w*32,+32). Linear dest, inverse-swizzled source.
    const int src_c   = w * 32 + (l >> 3);                 // h=0 row; +8 per h
    const int src_swz = ((l & 7) ^ ((l >> 3) & 7)) << 3;   // ushort offset within 64-m row
    #define STAGE(vb, mo)                                                                 \
        _Pragma("unroll")                                                                 \
        for (int h = 0; h < 4; ++h) {                                                     \
            const unsigned short* srcp = V + (size_t)(src_c + 8 * h) * N + (mo) + src_swz; \
            __builtin_amdgcn_global_load_lds(                                             \
                (const __attribute__((address_space(1))) unsigned*)srcp,                  \
                (__attribute__((address_space(3))) unsigned*)(&Vt[vb][(w * 32 + h * 8) * 64]), \
                16, 0, 0);                                                                \
        }

    STAGE(0, m_base)

    short8 kf[4], kfn[4];
    if (sw) {
        #pragma unroll
        for (int t = 0; t < 4; ++t)
            kf[t] = *(const short8*)(kt + (size_t)(m_base + 16 * t + lc) * C8 + 8 * g);
    }

    f32x4 acc[2][4];
    #pragma unroll
    for (int u = 0; u < 2; ++u)
        #pragma unroll
        for (int j = 0; j < 4; ++j) acc[u][j] = (f32x4){0.f, 0.f, 0.f, 0.f};
    float Lr = 0.f;

    for (int s = 0; s < NS; ++s) {
        const int m0 = m_base + s * KVB;
        const int pb = s & 1;

        if (sw) {
            if (s + 1 < NS) {   // K prefetch issued BEFORE S-MFMAs (latency window = S phase)
                #pragma unroll
                for (int t = 0; t < 4; ++t)
                    kfn[t] = *(const short8*)(kt + (size_t)(m0 + KVB + 16 * t + lc) * C8 + 8 * g);
            }
            f32x4 sv[4];
            #pragma unroll
            for (int t = 0; t < 4; ++t)
                sv[t] = __builtin_amdgcn_mfma_f32_16x16x32_bf16(kf[t], qf, (f32x4){0.f,0.f,0.f,0.f}, 0, 0, 0);

            // log2e folded into Q: P = exp2(sv) directly
            float pr[4][4];
            #pragma unroll
            for (int t = 0; t < 4; ++t)
                #pragma unroll
                for (int i = 0; i < 4; ++i) {
                    pr[t][i] = __builtin_amdgcn_exp2f(sv[t][i]);
                    Lr += pr[t][i];
                }
            #pragma unroll
            for (int t = 0; t < 4; ++t) {
                // m = 16t+4g+i; chunk = 2t+(g>>1), swizzled by col&7; half-chunk by g&1
                uint2_ u2;
                u2.x = packbf2(pr[t][0], pr[t][1]);
                u2.y = packbf2(pr[t][2], pr[t][3]);
                const int byte = col * 128 + ((((2 * t + (g >> 1)) ^ (col & 7)) << 4)) + ((g & 1) << 3);
                *(uint2_*)((char*)Pl[pb] + byte) = u2;
            }
        }

        __syncthreads();   // P[pb] visible; every wave's V stage for this step drained

        if (s + 1 < NS) STAGE(pb ^ 1, m0 + KVB)   // full-step latency window

        __builtin_amdgcn_s_setprio(1);
        short8 vf[2][2];
        #pragma unroll
        for (int u = 0; u < 2; ++u)
            #pragma unroll
            for (int kc = 0; kc < 2; ++kc)
                vf[u][kc] = *(const short8*)((const char*)Vt[pb]
                              + (w * 32 + u * 16 + lc) * 128 + (((kc * 4 + g) ^ (lc & 7)) << 4));
        #pragma unroll
        for (int kc = 0; kc < 2; ++kc) {
            short8 pf[4];
            #pragma unroll
            for (int j = 0; j < 4; ++j)
                pf[j] = *(const short8*)((const char*)Pl[pb]
                          + (j * 16 + lc) * 128 + (((kc * 4 + g) ^ (lc & 7)) << 4));
            #pragma unroll
            for (int u = 0; u < 2; ++u)
                #pragma unroll
                for (int j = 0; j < 4; ++j)
                    acc[u][j] = __builtin_amdgcn_mfma_f32_16x16x32_bf16(vf[u][kc], pf[j], acc[u][j], 0, 0, 0);
        }
        __builtin_amdgcn_s_setprio(0);

        if (sw && s + 1 < NS) {
            #pragma unroll
            for (int t = 0; t < 4; ++t) kf[t] = kfn[t];
        }
    }

    // ---- epilogue ----
    if (sw) {
        Lr += __shfl_xor(Lr, 16);
        Lr += __shfl_xor(Lr, 32);
    }
    const size_t blk = (size_t)(dir * 128 + qb) * SP + sp;
    unsigned short* ab = accb + blk * (256 * 64);
    #pragma unroll
    for (int u = 0; u < 2; ++u)
        #pragma unroll
        for (int j = 0; j < 4; ++j)
            #pragma unroll
            for (int i = 0; i < 4; ++i) {
                const int c  = w * 32 + u * 16 + 4 * g + i;
                const int nl = j * 16 + lc;
                ab[c * 64 + nl] = f2bf(acc[u][j][i]);
            }
    if (sw && l < 16) Lpart[blk * 64 + w * 16 + l] = Lr;
}

// ---------------- combine: out = gamma * (sum acc)/(sum L) + x ----------------
__global__ __launch_bounds__(256) void combine_kernel(
    const float* __restrict__ x,
    const unsigned short* __restrict__ accb,
    const float* __restrict__ Lpart,
    const float* __restrict__ gammaA, const float* __restrict__ gammaB,
    float* __restrict__ out, int SP)
{
    const int tid = blockIdx.x * 256 + threadIdx.x;    // 2^19 threads x 8 elems
    const int nl0 = (tid & 7) * 8;
    const int qb  = (tid >> 3) & 127;
    const int c   = (tid >> 10) & 255;
    const int dir = (tid >> 18) & 1;

    const size_t bb = (size_t)(dir * 128 + qb) * SP;
    float s[8], Ls[8];
    #pragma unroll
    for (int e = 0; e < 8; ++e) { s[e] = 0.f; Ls[e] = 0.f; }

    for (int sp = 0; sp < SP; ++sp) {
        const unsigned short* ap = accb + (bb + sp) * (256 * 64) + (size_t)c * 64 + nl0;
        const short8 av = *(const short8*)ap;
        const float* lp = Lpart + (bb + sp) * 64 + nl0;
        #pragma unroll
        for (int e = 0; e < 8; ++e) {
            s[e]  += bf2f((unsigned short)av[e]);
            Ls[e] += lp[e];
        }
    }

    const float gamma = dir ? gammaA[0] : gammaB[0];
    const size_t off = (size_t)c * N + qb * QBLK + nl0;
    const float* xp = x + off;
    float* op = out + (dir ? 0 : (size_t)CIN * N) + off;
    #pragma unroll
    for (int e = 0; e < 8; ++e) op[e] = gamma * s[e] / Ls[e] + xp[e];
}

extern "C" void kernel_launch(void* const* d_in, const int* in_sizes, int n_in,
                              void* d_out, int out_size, void* d_ws, size_t ws_size,
                              hipStream_t stream) {
    const float* x = (const float*)d_in[0];
    unsigned short* ws = (unsigned short*)d_ws;

    size_t needed4 = (size_t)PROJ_USHORTS * 2 + 4ull * 8388608 + 4ull * 65536;
    size_t needed2 = (size_t)PROJ_USHORTS * 2 + 2ull * 8388608 + 2ull * 65536;
    int SP = (ws_size >= needed4) ? 4 : (ws_size >= needed2) ? 2 : 1;

    unsigned short* accb = ws + PROJ_USHORTS;
    unsigned short* Wb   = accb;   // overlap: consumed by proj before attn writes accb
    float* Lpart = (float*)(ws + PROJ_USHORTS + (size_t)SP * 4194304);

    castw_kernel<<<160, 256, 0, stream>>>(
        (const float*)d_in[1], (const float*)d_in[3], (const float*)d_in[5],
        (const float*)d_in[7], (const float*)d_in[9], (const float*)d_in[11], Wb);

    proj_kernel<<<256, 512, 0, stream>>>(
        x, Wb,
        (const float*)d_in[2],  (const float*)d_in[4],  (const float*)d_in[6],
        (const float*)d_in[8],  (const float*)d_in[10], (const float*)d_in[12],
        ws);

    attn_kernel<<<256 * SP, 512, 0, stream>>>(ws, accb, Lpart, SP);

    combine_kernel<<<2048, 256, 0, stream>>>(
        x, accb, Lpart,
        (const float*)d_in[13], (const float*)d_in[14],
        (float*)d_out, SP);
}